// Round 13
// baseline (117.442 us; speedup 1.0000x reference)
//
#include <hip/hip_runtime.h>
#include <hip/hip_bf16.h>
#include <math.h>

#define B_ 2
#define L_ 2048
#define DIM_ 1024
#define HD_ 64
#define TH_ 14
#define TWO_PI_F 6.28318530717958647692f
#define QSCALE_F 0.1803368801111204f  /* 0.125 * log2(e) */

typedef __bf16 bf16_t;
typedef __bf16 bf16x8 __attribute__((ext_vector_type(8)));
typedef __bf16 bf16x4 __attribute__((ext_vector_type(4)));
typedef float f32x4 __attribute__((ext_vector_type(4)));
typedef float f32x16 __attribute__((ext_vector_type(16)));
typedef unsigned int u32x2 __attribute__((ext_vector_type(2)));

static __device__ __forceinline__ bf16_t f2b(float f) { return (bf16_t)f; }

static __device__ __forceinline__ float fexp2(float x) {
#if __has_builtin(__builtin_amdgcn_exp2f)
  return __builtin_amdgcn_exp2f(x);   // raw v_exp_f32; inputs bounded
#else
  return exp2f(x);
#endif
}

// packed f32x2 -> bf16x2 (RNE), one instruction
static __device__ __forceinline__ unsigned int cvtpk(float a, float b) {
  unsigned int r;
  asm("v_cvt_pk_bf16_f32 %0, %1, %2" : "=v"(r) : "v"(a), "v"(b));
  return r;
}

static __device__ __forceinline__ void gl16(const bf16_t* g, bf16_t* l) {
  __builtin_amdgcn_global_load_lds(
      (const __attribute__((address_space(1))) void*)g,
      (__attribute__((address_space(3))) void*)l, 16, 0, 0);
}

// half-swap: a' = (a.lo32, b.lo32), b' = (a.hi32, b.hi32)
static __device__ __forceinline__ void swap32(unsigned int& a, unsigned int& b) {
#if __has_builtin(__builtin_amdgcn_permlane32_swap)
  u32x2 r = __builtin_amdgcn_permlane32_swap(a, b, false, false);
  a = r[0];
  b = r[1];
#else
  const int l = (int)(threadIdx.x & 63);
  unsigned int bp_a = (unsigned int)__builtin_amdgcn_ds_bpermute((l ^ 32) << 2, (int)a);
  unsigned int bp_b = (unsigned int)__builtin_amdgcn_ds_bpermute((l ^ 32) << 2, (int)b);
  unsigned int na = (l < 32) ? a : bp_b;
  unsigned int nb = (l < 32) ? bp_a : b;
  a = na;
  b = nb;
#endif
}

// ---------------------------------------------------------------------------
// Fused prep: x->bf16 (blocks 0..4095), weight transposes (4096..7807),
// quantum state (7808..9855).
// ---------------------------------------------------------------------------
__global__ __launch_bounds__(256)
void k_prep(const float* __restrict__ x, const float* __restrict__ wq1,
            const float* __restrict__ bq1, const float* __restrict__ ln_g,
            const float* __restrict__ ln_b, const float* __restrict__ wq,
            const float* __restrict__ wk, const float* __restrict__ wv,
            const float* __restrict__ wo, bf16_t* __restrict__ xb,
            bf16_t* __restrict__ wt_qkv, bf16_t* __restrict__ wt_o,
            bf16_t* __restrict__ amp_b, float* __restrict__ phase) {
  __shared__ float tile[32][33];
  const int t = threadIdx.x;
  const int bid = blockIdx.x;
  if (bid < 4096) {
    const int i = bid * 256 + t;
    const float4 v4 = ((const float4*)x)[i];
    bf16x4 o = {f2b(v4.x), f2b(v4.y), f2b(v4.z), f2b(v4.w)};
    *(bf16x4*)(xb + 4 * (size_t)i) = o;
  } else if (bid < 7808) {
    const float* W;
    bf16_t* Wt;
    int N, kt, nt;
    if (bid < 6784) {
      int r = bid - 4096;
      const int which = r / 896;
      r -= which * 896;
      W = (which == 0) ? wq : (which == 1) ? wk : wv;
      Wt = wt_qkv + (size_t)which * 896 * 1024;
      N = 896;
      kt = r & 31;
      nt = r >> 5;
    } else {
      const int r = bid - 6784;
      W = wo;
      Wt = wt_o;
      N = 1024;
      kt = r & 31;
      nt = r >> 5;
    }
    const int tx = t & 31, ty = t >> 5;
    const int k0 = kt * 32, n0 = nt * 32;
    #pragma unroll
    for (int i = 0; i < 4; ++i)
      tile[ty + 8 * i][tx] = W[(size_t)(k0 + ty + 8 * i) * N + n0 + tx];
    __syncthreads();
    #pragma unroll
    for (int i = 0; i < 4; ++i)
      Wt[(size_t)(n0 + ty + 8 * i) * 1024 + k0 + tx] = f2b(tile[tx][ty + 8 * i]);
  } else {
    const int gw = ((bid - 7808) * 256 + t) >> 6;
    const int lane = t & 63;
    const int h = gw >> 12;
    const int bl = gw & 4095;
    const float xv = x[(size_t)bl * DIM_ + h * HD_ + lane];
    float acc0 = bq1[lane];
    float acc1 = bq1[64 + lane];
    #pragma unroll 16
    for (int kk = 0; kk < 64; ++kk) {
      const float xk = __shfl(xv, kk, 64);
      acc0 = fmaf(xk, wq1[kk * 128 + lane], acc0);
      acc1 = fmaf(xk, wq1[kk * 128 + 64 + lane], acc1);
    }
    float s = acc0 + acc1;
    #pragma unroll
    for (int off = 32; off > 0; off >>= 1) s += __shfl_xor(s, off, 64);
    const float mu = s * (1.0f / 128.0f);
    const float d0 = acc0 - mu, d1 = acc1 - mu;
    float vsum = d0 * d0 + d1 * d1;
    #pragma unroll
    for (int off = 32; off > 0; off >>= 1) vsum += __shfl_xor(vsum, off, 64);
    const float rstd = rsqrtf(vsum * (1.0f / 128.0f) + 1e-5f);
    const float av = tanhf(d0 * rstd * ln_g[lane] + ln_b[lane]);
    const float pv = tanhf(d1 * rstd * ln_g[64 + lane] + ln_b[64 + lane]);
    const size_t o = ((size_t)h * (B_ * L_) + bl) * HD_ + lane;
    amp_b[o] = f2b(av);
    phase[o] = pv;
  }
}

// ---------------------------------------------------------------------------
// Pure qkv GEMM, 256x128 tiles (grid 336 = 8*42: one residency round, no
// dispatch tail). 512 threads = 8 waves (4m x 2n). Hybrid buffering in 80KB
// LDS (= 160/2, still 2 blocks/CU): A double-buffered (2x32KB, latency
// hidden under compute), B single-buffered (16KB, L2-hot, exposed only
// across loop-back). m-major per XCD for L2 A-reuse.
// ---------------------------------------------------------------------------
__global__ __launch_bounds__(512)
void k_mm1q(const bf16_t* __restrict__ A, const bf16_t* __restrict__ Wt,
            bf16_t* __restrict__ qb, bf16_t* __restrict__ kb, bf16_t* __restrict__ vb) {
  __shared__ char smem[81920];
  const int t = threadIdx.x;
  const int lane = t & 63, w = t >> 6;    // w: 0..7
  const int bid = blockIdx.x;
  const int xcd = bid & 7, slot = bid >> 3;   // slot: 0..41
  bf16_t* Asm = (bf16_t*)smem;            // [2][256*64] (64KB)
  bf16_t* Bsm = (bf16_t*)(smem + 65536);  // 128*64 (16KB)
  const int wm = w >> 1, wn = w & 1;      // 4m x 2n
  const int l31 = lane & 31, hi = lane >> 5;
  const int m_blk = xcd * 2 + slot / 21;  // m-major within XCD: A-panel L2-hot
  const int n_blk = slot % 21;
  const int m0 = m_blk * 256;
  const int n0 = n_blk * 128;
  const int sr = t >> 3, scb = t & 7;     // sr: 0..63

  auto STAGE_A = [&](int buf, int k0) {
    #pragma unroll
    for (int qc = 0; qc < 4; ++qc) {      // A: 256 rows, dest linear in t
      const int r = sr + 64 * qc;
      const int c = (scb ^ (r & 7)) * 8;
      gl16(A + (size_t)(m0 + r) * 1024 + k0 + c, Asm + buf * 16384 + qc * 4096 + t * 8);
    }
  };
  auto STAGE_B = [&](int k0) {
    #pragma unroll
    for (int qc = 0; qc < 2; ++qc) {      // B: 128 rows
      const int r = sr + 64 * qc;
      const int c = (scb ^ (r & 7)) * 8;
      gl16(Wt + (size_t)(n0 + r) * 1024 + k0 + c, Bsm + qc * 4096 + t * 8);
    }
  };

  f32x16 acc[2][2] = {};
  STAGE_A(0, 0);
  STAGE_B(0);
  for (int kt = 0; kt < 16; ++kt) {
    asm volatile("s_waitcnt vmcnt(0)" ::: "memory");
    __builtin_amdgcn_sched_barrier(0);
    __builtin_amdgcn_s_barrier();   // A[kt&1]+B(kt) landed; A buf^1 reads done
    if (kt < 15) STAGE_A((kt & 1) ^ 1, (kt + 1) * 64);   // hidden under compute
    const char* Ac = (const char*)(Asm + (kt & 1) * 16384);
    const char* Bc = (const char*)Bsm;
    #pragma unroll
    for (int s = 0; s < 4; ++s) {
      const int ra0 = wm * 64 + l31, ra1 = ra0 + 32;
      const int rb0 = wn * 64 + l31, rb1 = rb0 + 32;
      const bf16x8 af0 = *(const bf16x8*)(Ac + ra0 * 128 + (((2 * s + hi) ^ (ra0 & 7)) << 4));
      const bf16x8 af1 = *(const bf16x8*)(Ac + ra1 * 128 + (((2 * s + hi) ^ (ra1 & 7)) << 4));
      const bf16x8 bf0 = *(const bf16x8*)(Bc + rb0 * 128 + (((2 * s + hi) ^ (rb0 & 7)) << 4));
      const bf16x8 bf1 = *(const bf16x8*)(Bc + rb1 * 128 + (((2 * s + hi) ^ (rb1 & 7)) << 4));
      // swapped operands: lane&31 = m (within 32), regs = n: e + 8*rp + 4*hi
      acc[0][0] = __builtin_amdgcn_mfma_f32_32x32x16_bf16(bf0, af0, acc[0][0], 0, 0, 0);
      acc[0][1] = __builtin_amdgcn_mfma_f32_32x32x16_bf16(bf1, af0, acc[0][1], 0, 0, 0);
      acc[1][0] = __builtin_amdgcn_mfma_f32_32x32x16_bf16(bf0, af1, acc[1][0], 0, 0, 0);
      acc[1][1] = __builtin_amdgcn_mfma_f32_32x32x16_bf16(bf1, af1, acc[1][1], 0, 0, 0);
    }
    __builtin_amdgcn_s_barrier();   // all waves done reading B(kt)
    if (kt < 15) STAGE_B((kt + 1) * 64);   // exposed only across loop-back
  }
  const int n0w = n0 + wn * 64;
  const int which = (n0 >= 1792) ? 2 : (n0 >= 896) ? 1 : 0;
  #pragma unroll
  for (int mi = 0; mi < 2; ++mi) {
    const int m = m0 + wm * 64 + mi * 32 + l31;
    const int bsel = m >> 11, ll = m & 2047;
    #pragma unroll
    for (int ni = 0; ni < 2; ++ni) {
      if (which == 2) {
        #pragma unroll
        for (int rp = 0; rp < 4; ++rp) {
          #pragma unroll
          for (int e = 0; e < 4; ++e) {
            const int nn = n0w + ni * 32 + 8 * rp + 4 * hi + e - 1792;
            const int head = nn >> 6, hd = nn & 63;
            vb[(((size_t)bsel * TH_ + head) * HD_ + hd) * L_ + ll] = f2b(acc[mi][ni][4 * rp + e]);
          }
        }
      } else {
        const float sc2 = (which == 0) ? QSCALE_F : 1.0f;
        bf16_t* dst = (which == 0) ? qb : kb;
        #pragma unroll
        for (int rp = 0; rp < 4; ++rp) {
          const int nb = n0w + ni * 32 + 8 * rp + 4 * hi;
          const int nn = nb - which * 896;
          const int head = nn >> 6, hd = nn & 63;
          bf16x4 pk;
          #pragma unroll
          for (int e = 0; e < 4; ++e) pk[e] = f2b(acc[mi][ni][4 * rp + e] * sc2);
          *(bf16x4*)(dst + (((size_t)bsel * TH_ + head) * L_ + ll) * HD_ + hd) = pk;
        }
      }
    }
  }
}

// ---------------------------------------------------------------------------
// Out-proj GEMM (32x32x16 MFMA + swapped-operand f32 epilogue + bias).
// m-major per XCD; double-buffered LDS, one barrier per K-step.
// ---------------------------------------------------------------------------
__global__ __launch_bounds__(256)
void k_mm0(const bf16_t* __restrict__ A, const bf16_t* __restrict__ Wt,
           const float* __restrict__ bias, float* __restrict__ outf) {
  __shared__ char smem[65536];
  bf16_t* Asm = (bf16_t*)smem;            // [2][128*64]
  bf16_t* Bsm = (bf16_t*)(smem + 32768);  // [2][128*64]
  const int t = threadIdx.x;
  const int lane = t & 63, w = t >> 6;
  const int wm = w >> 1, wn = w & 1;
  const int l31 = lane & 31, hi = lane >> 5;
  const int bid = blockIdx.x;
  const int xcd = bid & 7, slot = bid >> 3;     // 256 = 8*32
  const int m0 = (xcd * 4 + (slot >> 3)) * 128; // m-major within XCD
  const int n0 = (slot & 7) * 128;
  const int sr = t >> 3, scb = t & 7;

  auto STAGE = [&](int buf, int k0) {
    #pragma unroll
    for (int qc = 0; qc < 4; ++qc) {
      const int r = sr + 32 * qc;
      const int c = (scb ^ (r & 7)) * 8;
      gl16(A + (size_t)(m0 + r) * 1024 + k0 + c, Asm + buf * 8192 + w * 512 + qc * 2048);
      gl16(Wt + (size_t)(n0 + r) * 1024 + k0 + c, Bsm + buf * 8192 + w * 512 + qc * 2048);
    }
  };

  f32x16 acc[2][2] = {};
  STAGE(0, 0);
  for (int kt = 0; kt < 16; ++kt) {
    asm volatile("s_waitcnt vmcnt(0)" ::: "memory");
    __builtin_amdgcn_sched_barrier(0);
    __builtin_amdgcn_s_barrier();
    if (kt < 15) STAGE((kt & 1) ^ 1, (kt + 1) * 64);
    const char* Ac = (const char*)(Asm + (kt & 1) * 8192);
    const char* Bc = (const char*)(Bsm + (kt & 1) * 8192);
    #pragma unroll
    for (int s = 0; s < 4; ++s) {
      const int ra0 = wm * 64 + l31, ra1 = ra0 + 32;
      const int rb0 = wn * 64 + l31, rb1 = rb0 + 32;
      const bf16x8 af0 = *(const bf16x8*)(Ac + ra0 * 128 + (((2 * s + hi) ^ (ra0 & 7)) << 4));
      const bf16x8 af1 = *(const bf16x8*)(Ac + ra1 * 128 + (((2 * s + hi) ^ (ra1 & 7)) << 4));
      const bf16x8 bf0 = *(const bf16x8*)(Bc + rb0 * 128 + (((2 * s + hi) ^ (rb0 & 7)) << 4));
      const bf16x8 bf1 = *(const bf16x8*)(Bc + rb1 * 128 + (((2 * s + hi) ^ (rb1 & 7)) << 4));
      acc[0][0] = __builtin_amdgcn_mfma_f32_32x32x16_bf16(bf0, af0, acc[0][0], 0, 0, 0);
      acc[0][1] = __builtin_amdgcn_mfma_f32_32x32x16_bf16(bf1, af0, acc[0][1], 0, 0, 0);
      acc[1][0] = __builtin_amdgcn_mfma_f32_32x32x16_bf16(bf0, af1, acc[1][0], 0, 0, 0);
      acc[1][1] = __builtin_amdgcn_mfma_f32_32x32x16_bf16(bf1, af1, acc[1][1], 0, 0, 0);
    }
  }
  #pragma unroll
  for (int mi = 0; mi < 2; ++mi) {
    const int m = m0 + wm * 64 + mi * 32 + l31;
    #pragma unroll
    for (int ni = 0; ni < 2; ++ni) {
      #pragma unroll
      for (int rp = 0; rp < 4; ++rp) {
        const int nb = n0 + wn * 64 + ni * 32 + 8 * rp + 4 * hi;
        const float4 bv = *(const float4*)&bias[nb];
        float4 r4;
        r4.x = acc[mi][ni][4 * rp + 0] + bv.x;
        r4.y = acc[mi][ni][4 * rp + 1] + bv.y;
        r4.z = acc[mi][ni][4 * rp + 2] + bv.z;
        r4.w = acc[mi][ni][4 * rp + 3] + bv.w;
        *(float4*)&outf[(size_t)m * 1024 + nb] = r4;
      }
    }
  }
}

// ---------------------------------------------------------------------------
// Flash attention (blocks s<56: R4's exact 512-thread, in-block KV-split x2,
// 64KB LDS -> 2 blocks/CU) + quantum chunk attention (s>=56: 2 chunks/block,
// 24KB LDS each). Per XCD: 56 trad + 8 quantum. grid = 512 (= 8*64).
// ---------------------------------------------------------------------------
__global__ __launch_bounds__(512)
void k_flash2(const bf16_t* __restrict__ qg, const bf16_t* __restrict__ kg,
              const bf16_t* __restrict__ vt, bf16_t* __restrict__ catb,
              const bf16_t* __restrict__ A, const bf16_t* __restrict__ amp_b,
              const float* __restrict__ phase, const float* __restrict__ shifts,
              const float* __restrict__ freqs) {
  __shared__ char smem[65536];
  const int t = threadIdx.x;
  const int lane = t & 63, w = t >> 6;       // w: 0..7
  const int l31 = lane & 31, hi = lane >> 5;
  const int xcd = blockIdx.x & 7, s = blockIdx.x >> 3;   // s: 0..63
  if (s < 56) {
    // ================= traditional flash attention =================
    const int g2 = w >> 2, wl = w & 3;         // kv-group, wave-in-group
    const int tb = xcd * 56 + s;               // 0..447
    const int qblk = tb & 15, bh = tb >> 4;
    const int head = bh % TH_, b = bh / TH_;
    const size_t base = (size_t)bh * (L_ * HD_);
    const int q = qblk * 128 + wl * 32 + l31;
    const int tl = t & 255;              // thread index within group
    const int r0 = tl >> 3, cb0 = tl & 7;
    const int r1 = r0 + 32;
    const int c0 = (cb0 ^ (r0 & 7)) * 8;
    const int c1 = (cb0 ^ (r1 & 7)) * 8;
    const int ubase = wl * 512;
    // per-group buffers: K dbuf [2][4096], V dbuf [2][4096]  (32KB per group)
    bf16_t* Kg = (bf16_t*)(smem + g2 * 32768);
    bf16_t* Vg = (bf16_t*)(smem + g2 * 32768 + 16384);
    const int kt0 = g2 * 16;

    bf16x8 qf[4];
    #pragma unroll
    for (int slot = 0; slot < 4; ++slot)
      qf[slot] = *(const bf16x8*)(qg + base + (size_t)q * 64 + 16 * slot + 8 * hi);

    f32x16 oT[2] = {};
    float l_acc = 0.0f;

    {
      const bf16_t* ksrc = kg + base + (size_t)kt0 * 64 * 64;
      const bf16_t* vsrc = vt + base + kt0 * 64;
      gl16(ksrc + r0 * 64 + c0, Kg + ubase);
      gl16(ksrc + r1 * 64 + c1, Kg + ubase + 2048);
      gl16(vsrc + (size_t)r0 * L_ + c0, Vg + ubase);
      gl16(vsrc + (size_t)r1 * L_ + c1, Vg + ubase + 2048);
    }
    for (int kt = 0; kt < 16; ++kt) {
      const int cur = kt & 1;
      if (kt < 15) {
        const bf16_t* ksrc = kg + base + (size_t)(kt0 + kt + 1) * 64 * 64;
        const bf16_t* vsrc = vt + base + (kt0 + kt + 1) * 64;
        bf16_t* kd = Kg + (cur ^ 1) * 4096;
        bf16_t* vd = Vg + (cur ^ 1) * 4096;
        gl16(ksrc + r0 * 64 + c0, kd + ubase);
        gl16(ksrc + r1 * 64 + c1, kd + ubase + 2048);
        gl16(vsrc + (size_t)r0 * L_ + c0, vd + ubase);
        gl16(vsrc + (size_t)r1 * L_ + c1, vd + ubase + 2048);
        asm volatile("s_waitcnt vmcnt(4)" ::: "memory");
      } else {
        asm volatile("s_waitcnt vmcnt(0)" ::: "memory");
      }
      __builtin_amdgcn_sched_barrier(0);
      __builtin_amdgcn_s_barrier();
      const char* Kc = (const char*)(Kg + cur * 4096);
      const char* Vc = (const char*)(Vg + cur * 4096);
      f32x16 sT0 = {}, sT1 = {};
      __builtin_amdgcn_s_setprio(1);
      #pragma unroll
      for (int slot = 0; slot < 4; ++slot) {
        const int row0 = l31;
        const int row1 = 32 + l31;
        const bf16x8 kf0 = *(const bf16x8*)(Kc + row0 * 128 + (((2 * slot + hi) ^ (row0 & 7)) << 4));
        const bf16x8 kf1 = *(const bf16x8*)(Kc + row1 * 128 + (((2 * slot + hi) ^ (row1 & 7)) << 4));
        sT0 = __builtin_amdgcn_mfma_f32_32x32x16_bf16(kf0, qf[slot], sT0, 0, 0, 0);
        sT1 = __builtin_amdgcn_mfma_f32_32x32x16_bf16(kf1, qf[slot], sT1, 0, 0, 0);
      }
      __builtin_amdgcn_s_setprio(0);
      unsigned int W0[8], W1[8];
      float la = 0.0f;
      #pragma unroll
      for (int rp = 0; rp < 8; ++rp) {
        const float p00 = fexp2(sT0[2 * rp]);
        const float p01 = fexp2(sT0[2 * rp + 1]);
        const float p10 = fexp2(sT1[2 * rp]);
        const float p11 = fexp2(sT1[2 * rp + 1]);
        la += (p00 + p01) + (p10 + p11);
        W0[rp] = cvtpk(p00, p01);
        W1[rp] = cvtpk(p10, p11);
      }
      l_acc += la;
      unsigned int pb[4][4];
      #pragma unroll
      for (int m1 = 0; m1 < 2; ++m1) {
        unsigned int u, vv;
        u = W0[m1];     vv = W0[2 + m1]; swap32(u, vv); pb[0][m1] = u; pb[0][m1 + 2] = vv;
        u = W0[4 + m1]; vv = W0[6 + m1]; swap32(u, vv); pb[1][m1] = u; pb[1][m1 + 2] = vv;
        u = W1[m1];     vv = W1[2 + m1]; swap32(u, vv); pb[2][m1] = u; pb[2][m1 + 2] = vv;
        u = W1[4 + m1]; vv = W1[6 + m1]; swap32(u, vv); pb[3][m1] = u; pb[3][m1 + 2] = vv;
      }
      __builtin_amdgcn_s_setprio(1);
      #pragma unroll
      for (int slot = 0; slot < 4; ++slot) {
        union { unsigned int u[4]; bf16x8 v8; } pf;
        pf.u[0] = pb[slot][0]; pf.u[1] = pb[slot][1];
        pf.u[2] = pb[slot][2]; pf.u[3] = pb[slot][3];
        #pragma unroll
        for (int dt = 0; dt < 2; ++dt) {
          const int row = 32 * dt + l31;
          const bf16x8 vf = *(const bf16x8*)(Vc + row * 128 + (((2 * slot + hi) ^ (row & 7)) << 4));
          oT[dt] = __builtin_amdgcn_mfma_f32_32x32x16_bf16(vf, pf.v8, oT[dt], 0, 0, 0);
        }
      }
      __builtin_amdgcn_s_setprio(0);
      __builtin_amdgcn_s_barrier();
    }
    // ---- cross-group combine (pure addition: no running max anywhere) ----
    const float l_w = l_acc + __shfl_xor(l_acc, 32, 64);
    __syncthreads();                       // all loop-phase LDS reads complete
    float* obuf = (float*)(smem + 32768);  // [32][256] f32 = 32KB (group-1 area)
    float* lbuf = (float*)smem;            // [256] f32 (group-0 K area, now dead)
    if (g2 == 1) {
      #pragma unroll
      for (int dt = 0; dt < 2; ++dt)
        #pragma unroll
        for (int e = 0; e < 16; ++e)
          obuf[(dt * 16 + e) * 256 + wl * 64 + lane] = oT[dt][e];
      lbuf[wl * 64 + lane] = l_w;
    }
    __syncthreads();
    if (g2 == 0) {
      const float l_tot = l_w + lbuf[wl * 64 + lane];
      const float inv = 1.0f / l_tot;
      const size_t obase = ((size_t)b * L_ + q) * DIM_ + 128 + head * 64;
      #pragma unroll
      for (int dt = 0; dt < 2; ++dt) {
        #pragma unroll
        for (int rq = 0; rq < 4; ++rq) {
          bf16x4 pk;
          #pragma unroll
          for (int e = 0; e < 4; ++e)
            pk[e] = f2b((oT[dt][4 * rq + e] +
                         obuf[(dt * 16 + 4 * rq + e) * 256 + wl * 64 + lane]) * inv);
          *(bf16x4*)(catb + obase + 32 * dt + 8 * rq + 4 * hi) = pk;
        }
      }
    }
  } else {
    // ================= quantum chunk attention (2 chunks, 24KB LDS each) ===
    const int g3 = w >> 2, wl = w & 3;       // chunk-group, wave-in-group
    const int tl = t & 255;
    bf16_t* Kam = (bf16_t*)(smem + g3 * 24576);          // 64*64  (8KB)
    bf16_t* Vt2 = (bf16_t*)(smem + g3 * 24576 + 8192);   // 64*64  (8KB)
    bf16_t* Ps  = (bf16_t*)(smem + g3 * 24576 + 16384);  // 4*16*64 (8KB)
    const int l15 = lane & 15, g = lane >> 4;
    const int qp = xcd * 8 + (s - 56);       // 0..63
    const int qv = qp * 2 + g3;              // 0..127
    const int c = qv & 31;
    const int hb = qv >> 5;
    const int b = hb & 1;
    const int h = hb >> 1;
    const size_t abase = ((size_t)h * B_ + b) * L_ * HD_;

    {
      const int r0 = tl >> 3, cb0 = tl & 7;
      const int r1 = r0 + 32;
      gl16(amp_b + abase + r0 * 64 + (cb0 ^ (r0 & 7)) * 8, Kam + wl * 512);
      gl16(amp_b + abase + r1 * 64 + (cb0 ^ (r1 & 7)) * 8, Kam + wl * 512 + 2048);
    }
    {
      const int vj = tl >> 2;
      const int vd0 = (tl & 3) * 16;
      const bf16x8 va = *(const bf16x8*)(A + ((size_t)b * L_ + vj) * DIM_ + h * 64 + vd0);
      const bf16x8 vb2 = *(const bf16x8*)(A + ((size_t)b * L_ + vj) * DIM_ + h * 64 + vd0 + 8);
      #pragma unroll
      for (int e = 0; e < 8; ++e) {
        int d = vd0 + e;
        *(bf16_t*)((char*)Vt2 + d * 128 + (((vj >> 3) ^ (d & 7)) << 4) + (vj & 7) * 2) = va[e];
        d = vd0 + 8 + e;
        *(bf16_t*)((char*)Vt2 + d * 128 + (((vj >> 3) ^ (d & 7)) << 4) + (vj & 7) * 2) = vb2[e];
      }
    }
    __syncthreads();

    bf16x8 qf[2];
    {
      const size_t ro = abase + (size_t)(c * 64 + 16 * wl + l15) * 64 + g * 8;
      qf[0] = *(const bf16x8*)(amp_b + ro);
      qf[1] = *(const bf16x8*)(amp_b + ro + 32);
    }
    f32x4 sq[4] = {};
    #pragma unroll
    for (int ks = 0; ks < 2; ++ks) {
      #pragma unroll
      for (int nt = 0; nt < 4; ++nt) {
        const int jr = nt * 16 + l15;
        const bf16x8 kf = *(const bf16x8*)((char*)Kam + jr * 128 + (((ks * 4 + g) ^ (jr & 7)) << 4));
        sq[nt] = __builtin_amdgcn_mfma_f32_16x16x32_bf16(qf[ks], kf, sq[nt], 0, 0, 0);
      }
    }
    const float freq = freqs[h], shift = shifts[h];
    char* PsW = (char*)Ps + wl * 2048;
    float l_acc[4];
    #pragma unroll
    for (int r = 0; r < 4; ++r) {
      const int i_loc = 16 * wl + 4 * g + r;
      const float* qrow = phase + abase + (size_t)(c * 64 + i_loc) * 64;
      const float* krow = phase + abase + i_loc;   // kp[j][i_loc] = phase[abase + j*64 + i_loc]
      const int row = g * 4 + r;
      float ls = 0.0f;
      #pragma unroll
      for (int nt = 0; nt < 4; ++nt) {
        const int j = nt * 16 + l15;
        const float qp2 = qrow[j];
        const float kp = krow[j * 64];
        const float pd = (qp2 - kp) * freq + shift;
        const float t1 = pd * (2048.0f / TWO_PI_F);
        float mm = fmodf(t1, 2048.0f);
        if (mm < 0.0f) mm += 2048.0f;
        int idx = (int)mm;
        idx = idx > 2047 ? 2047 : idx;
        const float interf = cosf((float)idx * (TWO_PI_F / 2047.0f));
        const float sc = sq[nt][r] * interf * 0.125f;
        const float e = expf(sc);
        ls += e;
        *(bf16_t*)(PsW + row * 128 + (((j >> 3) ^ (row & 7)) << 4) + (j & 7) * 2) = f2b(e);
      }
      #pragma unroll
      for (int off = 1; off < 16; off <<= 1) ls += __shfl_xor(ls, off, 64);
      l_acc[r] = ls;
    }
    f32x4 o[4] = {};
    #pragma unroll
    for (int ks = 0; ks < 2; ++ks) {
      const bf16x8 pa = *(const bf16x8*)(PsW + l15 * 128 + (((ks * 4 + g) ^ (l15 & 7)) << 4));
      #pragma unroll
      for (int nt = 0; nt < 4; ++nt) {
        const int dr = nt * 16 + l15;
        const bf16x8 vf = *(const bf16x8*)((char*)Vt2 + dr * 128 + (((ks * 4 + g) ^ (dr & 7)) << 4));
        o[nt] = __builtin_amdgcn_mfma_f32_16x16x32_bf16(pa, vf, o[nt], 0, 0, 0);
      }
    }
    #pragma unroll
    for (int r = 0; r < 4; ++r) {
      const float inv = 1.0f / l_acc[r];
      const int qrow = c * 64 + 16 * wl + g * 4 + r;
      #pragma unroll
      for (int nt = 0; nt < 4; ++nt)
        catb[((size_t)b * L_ + qrow) * DIM_ + h * 64 + nt * 16 + l15] = f2b(o[nt][r] * inv);
    }
  }
}

// ---------------------------------------------------------------------------
extern "C" void kernel_launch(void* const* d_in, const int* in_sizes, int n_in,
                              void* d_out, int out_size, void* d_ws, size_t ws_size,
                              hipStream_t stream) {
  (void)in_sizes; (void)n_in; (void)out_size; (void)ws_size;
  const float* x      = (const float*)d_in[0];
  const float* wq1    = (const float*)d_in[1];
  const float* bq1    = (const float*)d_in[2];
  const float* ln_g   = (const float*)d_in[3];
  const float* ln_b   = (const float*)d_in[4];
  const float* shifts = (const float*)d_in[5];
  const float* freqs  = (const float*)d_in[6];
  const float* wq     = (const float*)d_in[7];
  const float* wk     = (const float*)d_in[8];
  const float* wv     = (const float*)d_in[9];
  const float* wo     = (const float*)d_in[10];
  const float* bo     = (const float*)d_in[11];
  float* out = (float*)d_out;

  char* p = (char*)d_ws;
  bf16_t* amp_b  = (bf16_t*)p; p += (size_t)2 * B_ * L_ * HD_ * 2;
  float* phase   = (float*)p;  p += (size_t)2 * B_ * L_ * HD_ * 4;
  bf16_t* xb     = (bf16_t*)p; p += (size_t)B_ * L_ * DIM_ * 2;
  bf16_t* wt_qkv = (bf16_t*)p; p += (size_t)2688 * 1024 * 2;
  bf16_t* wt_o   = (bf16_t*)p; p += (size_t)1024 * 1024 * 2;
  bf16_t* qb     = (bf16_t*)p; p += (size_t)B_ * TH_ * L_ * HD_ * 2;
  bf16_t* kb     = (bf16_t*)p; p += (size_t)B_ * TH_ * L_ * HD_ * 2;
  bf16_t* vtb    = (bf16_t*)p; p += (size_t)B_ * TH_ * L_ * HD_ * 2;
  bf16_t* catb   = (bf16_t*)p;

  k_prep<<<dim3(9856), dim3(256), 0, stream>>>(x, wq1, bq1, ln_g, ln_b,
                                               wq, wk, wv, wo,
                                               xb, wt_qkv, wt_o, amp_b, phase);
  k_mm1q<<<dim3(336), dim3(512), 0, stream>>>(xb, wt_qkv, qb, kb, vtb);
  k_flash2<<<dim3(512), dim3(512), 0, stream>>>(qb, kb, vtb, catb,
                                                xb, amp_b, phase, shifts, freqs);
  k_mm0<<<dim3(256), dim3(256), 0, stream>>>(catb, wt_o, bo, out);
}

// Round 14
// 116.163 us; speedup vs baseline: 1.0110x; 1.0110x over previous
//
#include <hip/hip_runtime.h>
#include <hip/hip_bf16.h>
#include <math.h>

#define B_ 2
#define L_ 2048
#define DIM_ 1024
#define HD_ 64
#define TH_ 14
#define TWO_PI_F 6.28318530717958647692f
#define QSCALE_F 0.1803368801111204f  /* 0.125 * log2(e) */

typedef __bf16 bf16_t;
typedef __bf16 bf16x8 __attribute__((ext_vector_type(8)));
typedef __bf16 bf16x4 __attribute__((ext_vector_type(4)));
typedef float f32x4 __attribute__((ext_vector_type(4)));
typedef float f32x16 __attribute__((ext_vector_type(16)));
typedef unsigned int u32x2 __attribute__((ext_vector_type(2)));

static __device__ __forceinline__ bf16_t f2b(float f) { return (bf16_t)f; }

static __device__ __forceinline__ float fexp2(float x) {
#if __has_builtin(__builtin_amdgcn_exp2f)
  return __builtin_amdgcn_exp2f(x);   // raw v_exp_f32; inputs bounded
#else
  return exp2f(x);
#endif
}

// packed f32x2 -> bf16x2 (RNE), one instruction
static __device__ __forceinline__ unsigned int cvtpk(float a, float b) {
  unsigned int r;
  asm("v_cvt_pk_bf16_f32 %0, %1, %2" : "=v"(r) : "v"(a), "v"(b));
  return r;
}

static __device__ __forceinline__ void gl16(const bf16_t* g, bf16_t* l) {
  __builtin_amdgcn_global_load_lds(
      (const __attribute__((address_space(1))) void*)g,
      (__attribute__((address_space(3))) void*)l, 16, 0, 0);
}

// half-swap: a' = (a.lo32, b.lo32), b' = (a.hi32, b.hi32)
static __device__ __forceinline__ void swap32(unsigned int& a, unsigned int& b) {
#if __has_builtin(__builtin_amdgcn_permlane32_swap)
  u32x2 r = __builtin_amdgcn_permlane32_swap(a, b, false, false);
  a = r[0];
  b = r[1];
#else
  const int l = (int)(threadIdx.x & 63);
  unsigned int bp_a = (unsigned int)__builtin_amdgcn_ds_bpermute((l ^ 32) << 2, (int)a);
  unsigned int bp_b = (unsigned int)__builtin_amdgcn_ds_bpermute((l ^ 32) << 2, (int)b);
  unsigned int na = (l < 32) ? a : bp_b;
  unsigned int nb = (l < 32) ? bp_a : b;
  a = na;
  b = nb;
#endif
}

// ---------------------------------------------------------------------------
// Fused prep: x->bf16 (blocks 0..4095), weight transposes (4096..7807),
// quantum state (7808..9855).
// ---------------------------------------------------------------------------
__global__ __launch_bounds__(256)
void k_prep(const float* __restrict__ x, const float* __restrict__ wq1,
            const float* __restrict__ bq1, const float* __restrict__ ln_g,
            const float* __restrict__ ln_b, const float* __restrict__ wq,
            const float* __restrict__ wk, const float* __restrict__ wv,
            const float* __restrict__ wo, bf16_t* __restrict__ xb,
            bf16_t* __restrict__ wt_qkv, bf16_t* __restrict__ wt_o,
            bf16_t* __restrict__ amp_b, float* __restrict__ phase) {
  __shared__ float tile[32][33];
  const int t = threadIdx.x;
  const int bid = blockIdx.x;
  if (bid < 4096) {
    const int i = bid * 256 + t;
    const float4 v4 = ((const float4*)x)[i];
    bf16x4 o = {f2b(v4.x), f2b(v4.y), f2b(v4.z), f2b(v4.w)};
    *(bf16x4*)(xb + 4 * (size_t)i) = o;
  } else if (bid < 7808) {
    const float* W;
    bf16_t* Wt;
    int N, kt, nt;
    if (bid < 6784) {
      int r = bid - 4096;
      const int which = r / 896;
      r -= which * 896;
      W = (which == 0) ? wq : (which == 1) ? wk : wv;
      Wt = wt_qkv + (size_t)which * 896 * 1024;
      N = 896;
      kt = r & 31;
      nt = r >> 5;
    } else {
      const int r = bid - 6784;
      W = wo;
      Wt = wt_o;
      N = 1024;
      kt = r & 31;
      nt = r >> 5;
    }
    const int tx = t & 31, ty = t >> 5;
    const int k0 = kt * 32, n0 = nt * 32;
    #pragma unroll
    for (int i = 0; i < 4; ++i)
      tile[ty + 8 * i][tx] = W[(size_t)(k0 + ty + 8 * i) * N + n0 + tx];
    __syncthreads();
    #pragma unroll
    for (int i = 0; i < 4; ++i)
      Wt[(size_t)(n0 + ty + 8 * i) * 1024 + k0 + tx] = f2b(tile[tx][ty + 8 * i]);
  } else {
    const int gw = ((bid - 7808) * 256 + t) >> 6;
    const int lane = t & 63;
    const int h = gw >> 12;
    const int bl = gw & 4095;
    const float xv = x[(size_t)bl * DIM_ + h * HD_ + lane];
    float acc0 = bq1[lane];
    float acc1 = bq1[64 + lane];
    #pragma unroll 16
    for (int kk = 0; kk < 64; ++kk) {
      const float xk = __shfl(xv, kk, 64);
      acc0 = fmaf(xk, wq1[kk * 128 + lane], acc0);
      acc1 = fmaf(xk, wq1[kk * 128 + 64 + lane], acc1);
    }
    float s = acc0 + acc1;
    #pragma unroll
    for (int off = 32; off > 0; off >>= 1) s += __shfl_xor(s, off, 64);
    const float mu = s * (1.0f / 128.0f);
    const float d0 = acc0 - mu, d1 = acc1 - mu;
    float vsum = d0 * d0 + d1 * d1;
    #pragma unroll
    for (int off = 32; off > 0; off >>= 1) vsum += __shfl_xor(vsum, off, 64);
    const float rstd = rsqrtf(vsum * (1.0f / 128.0f) + 1e-5f);
    const float av = tanhf(d0 * rstd * ln_g[lane] + ln_b[lane]);
    const float pv = tanhf(d1 * rstd * ln_g[64 + lane] + ln_b[64 + lane]);
    const size_t o = ((size_t)h * (B_ * L_) + bl) * HD_ + lane;
    amp_b[o] = f2b(av);
    phase[o] = pv;
  }
}

// ---------------------------------------------------------------------------
// Pure qkv GEMM, 256x128 tiles (grid 336 = 8*42: ALL blocks co-resident in
// one residency round, no dispatch tail). 512 threads = 8 waves (4m x 2n).
// Single-buffer 48KB LDS (>=2 blocks/CU), 2 barriers per K-step.
// m-major per XCD for L2 A-reuse.
// ---------------------------------------------------------------------------
__global__ __launch_bounds__(512)
void k_mm1q(const bf16_t* __restrict__ A, const bf16_t* __restrict__ Wt,
            bf16_t* __restrict__ qb, bf16_t* __restrict__ kb, bf16_t* __restrict__ vb) {
  __shared__ char smem[49152];
  const int t = threadIdx.x;
  const int lane = t & 63, w = t >> 6;    // w: 0..7
  const int bid = blockIdx.x;
  const int xcd = bid & 7, slot = bid >> 3;   // slot: 0..41
  bf16_t* Asm = (bf16_t*)smem;            // 256*64 (32KB)
  bf16_t* Bsm = (bf16_t*)(smem + 32768);  // 128*64 (16KB)
  const int wm = w >> 1, wn = w & 1;      // 4m x 2n
  const int l31 = lane & 31, hi = lane >> 5;
  const int m_blk = xcd * 2 + slot / 21;  // m-major within XCD: A-panel L2-hot
  const int n_blk = slot % 21;
  const int m0 = m_blk * 256;
  const int n0 = n_blk * 128;
  const int sr = t >> 3, scb = t & 7;     // sr: 0..63

  auto STAGE = [&](int k0) {
    #pragma unroll
    for (int qc = 0; qc < 4; ++qc) {      // A: 256 rows, dest linear in t
      const int r = sr + 64 * qc;
      const int c = (scb ^ (r & 7)) * 8;
      gl16(A + (size_t)(m0 + r) * 1024 + k0 + c, Asm + qc * 4096 + t * 8);
    }
    #pragma unroll
    for (int qc = 0; qc < 2; ++qc) {      // B: 128 rows
      const int r = sr + 64 * qc;
      const int c = (scb ^ (r & 7)) * 8;
      gl16(Wt + (size_t)(n0 + r) * 1024 + k0 + c, Bsm + qc * 4096 + t * 8);
    }
  };

  f32x16 acc[2][2] = {};
  for (int kt = 0; kt < 16; ++kt) {
    if (kt > 0) __syncthreads();          // WAR: prev compute reads done
    STAGE(kt * 64);
    asm volatile("s_waitcnt vmcnt(0)" ::: "memory");
    __builtin_amdgcn_sched_barrier(0);
    __builtin_amdgcn_s_barrier();         // tile data landed for all waves
    const char* Ac = (const char*)Asm;
    const char* Bc = (const char*)Bsm;
    #pragma unroll
    for (int s = 0; s < 4; ++s) {
      const int ra0 = wm * 64 + l31, ra1 = ra0 + 32;
      const int rb0 = wn * 64 + l31, rb1 = rb0 + 32;
      const bf16x8 af0 = *(const bf16x8*)(Ac + ra0 * 128 + (((2 * s + hi) ^ (ra0 & 7)) << 4));
      const bf16x8 af1 = *(const bf16x8*)(Ac + ra1 * 128 + (((2 * s + hi) ^ (ra1 & 7)) << 4));
      const bf16x8 bf0 = *(const bf16x8*)(Bc + rb0 * 128 + (((2 * s + hi) ^ (rb0 & 7)) << 4));
      const bf16x8 bf1 = *(const bf16x8*)(Bc + rb1 * 128 + (((2 * s + hi) ^ (rb1 & 7)) << 4));
      // swapped operands: lane&31 = m (within 32), regs = n: e + 8*rp + 4*hi
      acc[0][0] = __builtin_amdgcn_mfma_f32_32x32x16_bf16(bf0, af0, acc[0][0], 0, 0, 0);
      acc[0][1] = __builtin_amdgcn_mfma_f32_32x32x16_bf16(bf1, af0, acc[0][1], 0, 0, 0);
      acc[1][0] = __builtin_amdgcn_mfma_f32_32x32x16_bf16(bf0, af1, acc[1][0], 0, 0, 0);
      acc[1][1] = __builtin_amdgcn_mfma_f32_32x32x16_bf16(bf1, af1, acc[1][1], 0, 0, 0);
    }
  }
  const int n0w = n0 + wn * 64;
  const int which = (n0 >= 1792) ? 2 : (n0 >= 896) ? 1 : 0;
  #pragma unroll
  for (int mi = 0; mi < 2; ++mi) {
    const int m = m0 + wm * 64 + mi * 32 + l31;
    const int bsel = m >> 11, ll = m & 2047;
    #pragma unroll
    for (int ni = 0; ni < 2; ++ni) {
      if (which == 2) {
        #pragma unroll
        for (int rp = 0; rp < 4; ++rp) {
          #pragma unroll
          for (int e = 0; e < 4; ++e) {
            const int nn = n0w + ni * 32 + 8 * rp + 4 * hi + e - 1792;
            const int head = nn >> 6, hd = nn & 63;
            vb[(((size_t)bsel * TH_ + head) * HD_ + hd) * L_ + ll] = f2b(acc[mi][ni][4 * rp + e]);
          }
        }
      } else {
        const float sc2 = (which == 0) ? QSCALE_F : 1.0f;
        bf16_t* dst = (which == 0) ? qb : kb;
        #pragma unroll
        for (int rp = 0; rp < 4; ++rp) {
          const int nb = n0w + ni * 32 + 8 * rp + 4 * hi;
          const int nn = nb - which * 896;
          const int head = nn >> 6, hd = nn & 63;
          bf16x4 pk;
          #pragma unroll
          for (int e = 0; e < 4; ++e) pk[e] = f2b(acc[mi][ni][4 * rp + e] * sc2);
          *(bf16x4*)(dst + (((size_t)bsel * TH_ + head) * L_ + ll) * HD_ + hd) = pk;
        }
      }
    }
  }
}

// ---------------------------------------------------------------------------
// Out-proj GEMM (32x32x16 MFMA + swapped-operand f32 epilogue + bias).
// m-major per XCD; double-buffered LDS, one barrier per K-step.
// ---------------------------------------------------------------------------
__global__ __launch_bounds__(256)
void k_mm0(const bf16_t* __restrict__ A, const bf16_t* __restrict__ Wt,
           const float* __restrict__ bias, float* __restrict__ outf) {
  __shared__ char smem[65536];
  bf16_t* Asm = (bf16_t*)smem;            // [2][128*64]
  bf16_t* Bsm = (bf16_t*)(smem + 32768);  // [2][128*64]
  const int t = threadIdx.x;
  const int lane = t & 63, w = t >> 6;
  const int wm = w >> 1, wn = w & 1;
  const int l31 = lane & 31, hi = lane >> 5;
  const int bid = blockIdx.x;
  const int xcd = bid & 7, slot = bid >> 3;     // 256 = 8*32
  const int m0 = (xcd * 4 + (slot >> 3)) * 128; // m-major within XCD
  const int n0 = (slot & 7) * 128;
  const int sr = t >> 3, scb = t & 7;

  auto STAGE = [&](int buf, int k0) {
    #pragma unroll
    for (int qc = 0; qc < 4; ++qc) {
      const int r = sr + 32 * qc;
      const int c = (scb ^ (r & 7)) * 8;
      gl16(A + (size_t)(m0 + r) * 1024 + k0 + c, Asm + buf * 8192 + w * 512 + qc * 2048);
      gl16(Wt + (size_t)(n0 + r) * 1024 + k0 + c, Bsm + buf * 8192 + w * 512 + qc * 2048);
    }
  };

  f32x16 acc[2][2] = {};
  STAGE(0, 0);
  for (int kt = 0; kt < 16; ++kt) {
    asm volatile("s_waitcnt vmcnt(0)" ::: "memory");
    __builtin_amdgcn_sched_barrier(0);
    __builtin_amdgcn_s_barrier();
    if (kt < 15) STAGE((kt & 1) ^ 1, (kt + 1) * 64);
    const char* Ac = (const char*)(Asm + (kt & 1) * 8192);
    const char* Bc = (const char*)(Bsm + (kt & 1) * 8192);
    #pragma unroll
    for (int s = 0; s < 4; ++s) {
      const int ra0 = wm * 64 + l31, ra1 = ra0 + 32;
      const int rb0 = wn * 64 + l31, rb1 = rb0 + 32;
      const bf16x8 af0 = *(const bf16x8*)(Ac + ra0 * 128 + (((2 * s + hi) ^ (ra0 & 7)) << 4));
      const bf16x8 af1 = *(const bf16x8*)(Ac + ra1 * 128 + (((2 * s + hi) ^ (ra1 & 7)) << 4));
      const bf16x8 bf0 = *(const bf16x8*)(Bc + rb0 * 128 + (((2 * s + hi) ^ (rb0 & 7)) << 4));
      const bf16x8 bf1 = *(const bf16x8*)(Bc + rb1 * 128 + (((2 * s + hi) ^ (rb1 & 7)) << 4));
      acc[0][0] = __builtin_amdgcn_mfma_f32_32x32x16_bf16(bf0, af0, acc[0][0], 0, 0, 0);
      acc[0][1] = __builtin_amdgcn_mfma_f32_32x32x16_bf16(bf1, af0, acc[0][1], 0, 0, 0);
      acc[1][0] = __builtin_amdgcn_mfma_f32_32x32x16_bf16(bf0, af1, acc[1][0], 0, 0, 0);
      acc[1][1] = __builtin_amdgcn_mfma_f32_32x32x16_bf16(bf1, af1, acc[1][1], 0, 0, 0);
    }
  }
  #pragma unroll
  for (int mi = 0; mi < 2; ++mi) {
    const int m = m0 + wm * 64 + mi * 32 + l31;
    #pragma unroll
    for (int ni = 0; ni < 2; ++ni) {
      #pragma unroll
      for (int rp = 0; rp < 4; ++rp) {
        const int nb = n0 + wn * 64 + ni * 32 + 8 * rp + 4 * hi;
        const float4 bv = *(const float4*)&bias[nb];
        float4 r4;
        r4.x = acc[mi][ni][4 * rp + 0] + bv.x;
        r4.y = acc[mi][ni][4 * rp + 1] + bv.y;
        r4.z = acc[mi][ni][4 * rp + 2] + bv.z;
        r4.w = acc[mi][ni][4 * rp + 3] + bv.w;
        *(float4*)&outf[(size_t)m * 1024 + nb] = r4;
      }
    }
  }
}

// ---------------------------------------------------------------------------
// Flash attention (blocks s<56: R4's exact 512-thread, in-block KV-split x2,
// 64KB LDS -> 2 blocks/CU) + quantum chunk attention (s>=56: 2 chunks/block,
// 24KB LDS each). Per XCD: 56 trad + 8 quantum. grid = 512 (= 8*64).
// ---------------------------------------------------------------------------
__global__ __launch_bounds__(512)
void k_flash2(const bf16_t* __restrict__ qg, const bf16_t* __restrict__ kg,
              const bf16_t* __restrict__ vt, bf16_t* __restrict__ catb,
              const bf16_t* __restrict__ A, const bf16_t* __restrict__ amp_b,
              const float* __restrict__ phase, const float* __restrict__ shifts,
              const float* __restrict__ freqs) {
  __shared__ char smem[65536];
  const int t = threadIdx.x;
  const int lane = t & 63, w = t >> 6;       // w: 0..7
  const int l31 = lane & 31, hi = lane >> 5;
  const int xcd = blockIdx.x & 7, s = blockIdx.x >> 3;   // s: 0..63
  if (s < 56) {
    // ================= traditional flash attention =================
    const int g2 = w >> 2, wl = w & 3;         // kv-group, wave-in-group
    const int tb = xcd * 56 + s;               // 0..447
    const int qblk = tb & 15, bh = tb >> 4;
    const int head = bh % TH_, b = bh / TH_;
    const size_t base = (size_t)bh * (L_ * HD_);
    const int q = qblk * 128 + wl * 32 + l31;
    const int tl = t & 255;              // thread index within group
    const int r0 = tl >> 3, cb0 = tl & 7;
    const int r1 = r0 + 32;
    const int c0 = (cb0 ^ (r0 & 7)) * 8;
    const int c1 = (cb0 ^ (r1 & 7)) * 8;
    const int ubase = wl * 512;
    // per-group buffers: K dbuf [2][4096], V dbuf [2][4096]  (32KB per group)
    bf16_t* Kg = (bf16_t*)(smem + g2 * 32768);
    bf16_t* Vg = (bf16_t*)(smem + g2 * 32768 + 16384);
    const int kt0 = g2 * 16;

    bf16x8 qf[4];
    #pragma unroll
    for (int slot = 0; slot < 4; ++slot)
      qf[slot] = *(const bf16x8*)(qg + base + (size_t)q * 64 + 16 * slot + 8 * hi);

    f32x16 oT[2] = {};
    float l_acc = 0.0f;

    {
      const bf16_t* ksrc = kg + base + (size_t)kt0 * 64 * 64;
      const bf16_t* vsrc = vt + base + kt0 * 64;
      gl16(ksrc + r0 * 64 + c0, Kg + ubase);
      gl16(ksrc + r1 * 64 + c1, Kg + ubase + 2048);
      gl16(vsrc + (size_t)r0 * L_ + c0, Vg + ubase);
      gl16(vsrc + (size_t)r1 * L_ + c1, Vg + ubase + 2048);
    }
    for (int kt = 0; kt < 16; ++kt) {
      const int cur = kt & 1;
      if (kt < 15) {
        const bf16_t* ksrc = kg + base + (size_t)(kt0 + kt + 1) * 64 * 64;
        const bf16_t* vsrc = vt + base + (kt0 + kt + 1) * 64;
        bf16_t* kd = Kg + (cur ^ 1) * 4096;
        bf16_t* vd = Vg + (cur ^ 1) * 4096;
        gl16(ksrc + r0 * 64 + c0, kd + ubase);
        gl16(ksrc + r1 * 64 + c1, kd + ubase + 2048);
        gl16(vsrc + (size_t)r0 * L_ + c0, vd + ubase);
        gl16(vsrc + (size_t)r1 * L_ + c1, vd + ubase + 2048);
        asm volatile("s_waitcnt vmcnt(4)" ::: "memory");
      } else {
        asm volatile("s_waitcnt vmcnt(0)" ::: "memory");
      }
      __builtin_amdgcn_sched_barrier(0);
      __builtin_amdgcn_s_barrier();
      const char* Kc = (const char*)(Kg + cur * 4096);
      const char* Vc = (const char*)(Vg + cur * 4096);
      f32x16 sT0 = {}, sT1 = {};
      __builtin_amdgcn_s_setprio(1);
      #pragma unroll
      for (int slot = 0; slot < 4; ++slot) {
        const int row0 = l31;
        const int row1 = 32 + l31;
        const bf16x8 kf0 = *(const bf16x8*)(Kc + row0 * 128 + (((2 * slot + hi) ^ (row0 & 7)) << 4));
        const bf16x8 kf1 = *(const bf16x8*)(Kc + row1 * 128 + (((2 * slot + hi) ^ (row1 & 7)) << 4));
        sT0 = __builtin_amdgcn_mfma_f32_32x32x16_bf16(kf0, qf[slot], sT0, 0, 0, 0);
        sT1 = __builtin_amdgcn_mfma_f32_32x32x16_bf16(kf1, qf[slot], sT1, 0, 0, 0);
      }
      __builtin_amdgcn_s_setprio(0);
      unsigned int W0[8], W1[8];
      float la = 0.0f;
      #pragma unroll
      for (int rp = 0; rp < 8; ++rp) {
        const float p00 = fexp2(sT0[2 * rp]);
        const float p01 = fexp2(sT0[2 * rp + 1]);
        const float p10 = fexp2(sT1[2 * rp]);
        const float p11 = fexp2(sT1[2 * rp + 1]);
        la += (p00 + p01) + (p10 + p11);
        W0[rp] = cvtpk(p00, p01);
        W1[rp] = cvtpk(p10, p11);
      }
      l_acc += la;
      unsigned int pb[4][4];
      #pragma unroll
      for (int m1 = 0; m1 < 2; ++m1) {
        unsigned int u, vv;
        u = W0[m1];     vv = W0[2 + m1]; swap32(u, vv); pb[0][m1] = u; pb[0][m1 + 2] = vv;
        u = W0[4 + m1]; vv = W0[6 + m1]; swap32(u, vv); pb[1][m1] = u; pb[1][m1 + 2] = vv;
        u = W1[m1];     vv = W1[2 + m1]; swap32(u, vv); pb[2][m1] = u; pb[2][m1 + 2] = vv;
        u = W1[4 + m1]; vv = W1[6 + m1]; swap32(u, vv); pb[3][m1] = u; pb[3][m1 + 2] = vv;
      }
      __builtin_amdgcn_s_setprio(1);
      #pragma unroll
      for (int slot = 0; slot < 4; ++slot) {
        union { unsigned int u[4]; bf16x8 v8; } pf;
        pf.u[0] = pb[slot][0]; pf.u[1] = pb[slot][1];
        pf.u[2] = pb[slot][2]; pf.u[3] = pb[slot][3];
        #pragma unroll
        for (int dt = 0; dt < 2; ++dt) {
          const int row = 32 * dt + l31;
          const bf16x8 vf = *(const bf16x8*)(Vc + row * 128 + (((2 * slot + hi) ^ (row & 7)) << 4));
          oT[dt] = __builtin_amdgcn_mfma_f32_32x32x16_bf16(vf, pf.v8, oT[dt], 0, 0, 0);
        }
      }
      __builtin_amdgcn_s_setprio(0);
      __builtin_amdgcn_s_barrier();
    }
    // ---- cross-group combine (pure addition: no running max anywhere) ----
    const float l_w = l_acc + __shfl_xor(l_acc, 32, 64);
    __syncthreads();                       // all loop-phase LDS reads complete
    float* obuf = (float*)(smem + 32768);  // [32][256] f32 = 32KB (group-1 area)
    float* lbuf = (float*)smem;            // [256] f32 (group-0 K area, now dead)
    if (g2 == 1) {
      #pragma unroll
      for (int dt = 0; dt < 2; ++dt)
        #pragma unroll
        for (int e = 0; e < 16; ++e)
          obuf[(dt * 16 + e) * 256 + wl * 64 + lane] = oT[dt][e];
      lbuf[wl * 64 + lane] = l_w;
    }
    __syncthreads();
    if (g2 == 0) {
      const float l_tot = l_w + lbuf[wl * 64 + lane];
      const float inv = 1.0f / l_tot;
      const size_t obase = ((size_t)b * L_ + q) * DIM_ + 128 + head * 64;
      #pragma unroll
      for (int dt = 0; dt < 2; ++dt) {
        #pragma unroll
        for (int rq = 0; rq < 4; ++rq) {
          bf16x4 pk;
          #pragma unroll
          for (int e = 0; e < 4; ++e)
            pk[e] = f2b((oT[dt][4 * rq + e] +
                         obuf[(dt * 16 + 4 * rq + e) * 256 + wl * 64 + lane]) * inv);
          *(bf16x4*)(catb + obase + 32 * dt + 8 * rq + 4 * hi) = pk;
        }
      }
    }
  } else {
    // ================= quantum chunk attention (2 chunks, 24KB LDS each) ===
    const int g3 = w >> 2, wl = w & 3;       // chunk-group, wave-in-group
    const int tl = t & 255;
    bf16_t* Kam = (bf16_t*)(smem + g3 * 24576);          // 64*64  (8KB)
    bf16_t* Vt2 = (bf16_t*)(smem + g3 * 24576 + 8192);   // 64*64  (8KB)
    bf16_t* Ps  = (bf16_t*)(smem + g3 * 24576 + 16384);  // 4*16*64 (8KB)
    const int l15 = lane & 15, g = lane >> 4;
    const int qp = xcd * 8 + (s - 56);       // 0..63
    const int qv = qp * 2 + g3;              // 0..127
    const int c = qv & 31;
    const int hb = qv >> 5;
    const int b = hb & 1;
    const int h = hb >> 1;
    const size_t abase = ((size_t)h * B_ + b) * L_ * HD_;

    {
      const int r0 = tl >> 3, cb0 = tl & 7;
      const int r1 = r0 + 32;
      gl16(amp_b + abase + r0 * 64 + (cb0 ^ (r0 & 7)) * 8, Kam + wl * 512);
      gl16(amp_b + abase + r1 * 64 + (cb0 ^ (r1 & 7)) * 8, Kam + wl * 512 + 2048);
    }
    {
      const int vj = tl >> 2;
      const int vd0 = (tl & 3) * 16;
      const bf16x8 va = *(const bf16x8*)(A + ((size_t)b * L_ + vj) * DIM_ + h * 64 + vd0);
      const bf16x8 vb2 = *(const bf16x8*)(A + ((size_t)b * L_ + vj) * DIM_ + h * 64 + vd0 + 8);
      #pragma unroll
      for (int e = 0; e < 8; ++e) {
        int d = vd0 + e;
        *(bf16_t*)((char*)Vt2 + d * 128 + (((vj >> 3) ^ (d & 7)) << 4) + (vj & 7) * 2) = va[e];
        d = vd0 + 8 + e;
        *(bf16_t*)((char*)Vt2 + d * 128 + (((vj >> 3) ^ (d & 7)) << 4) + (vj & 7) * 2) = vb2[e];
      }
    }
    __syncthreads();

    bf16x8 qf[2];
    {
      const size_t ro = abase + (size_t)(c * 64 + 16 * wl + l15) * 64 + g * 8;
      qf[0] = *(const bf16x8*)(amp_b + ro);
      qf[1] = *(const bf16x8*)(amp_b + ro + 32);
    }
    f32x4 sq[4] = {};
    #pragma unroll
    for (int ks = 0; ks < 2; ++ks) {
      #pragma unroll
      for (int nt = 0; nt < 4; ++nt) {
        const int jr = nt * 16 + l15;
        const bf16x8 kf = *(const bf16x8*)((char*)Kam + jr * 128 + (((ks * 4 + g) ^ (jr & 7)) << 4));
        sq[nt] = __builtin_amdgcn_mfma_f32_16x16x32_bf16(qf[ks], kf, sq[nt], 0, 0, 0);
      }
    }
    const float freq = freqs[h], shift = shifts[h];
    char* PsW = (char*)Ps + wl * 2048;
    float l_acc[4];
    #pragma unroll
    for (int r = 0; r < 4; ++r) {
      const int i_loc = 16 * wl + 4 * g + r;
      const float* qrow = phase + abase + (size_t)(c * 64 + i_loc) * 64;
      const float* krow = phase + abase + i_loc;   // kp[j][i_loc] = phase[abase + j*64 + i_loc]
      const int row = g * 4 + r;
      float ls = 0.0f;
      #pragma unroll
      for (int nt = 0; nt < 4; ++nt) {
        const int j = nt * 16 + l15;
        const float qp2 = qrow[j];
        const float kp = krow[j * 64];
        const float pd = (qp2 - kp) * freq + shift;
        const float t1 = pd * (2048.0f / TWO_PI_F);
        float mm = fmodf(t1, 2048.0f);
        if (mm < 0.0f) mm += 2048.0f;
        int idx = (int)mm;
        idx = idx > 2047 ? 2047 : idx;
        const float interf = cosf((float)idx * (TWO_PI_F / 2047.0f));
        const float sc = sq[nt][r] * interf * 0.125f;
        const float e = expf(sc);
        ls += e;
        *(bf16_t*)(PsW + row * 128 + (((j >> 3) ^ (row & 7)) << 4) + (j & 7) * 2) = f2b(e);
      }
      #pragma unroll
      for (int off = 1; off < 16; off <<= 1) ls += __shfl_xor(ls, off, 64);
      l_acc[r] = ls;
    }
    f32x4 o[4] = {};
    #pragma unroll
    for (int ks = 0; ks < 2; ++ks) {
      const bf16x8 pa = *(const bf16x8*)(PsW + l15 * 128 + (((ks * 4 + g) ^ (l15 & 7)) << 4));
      #pragma unroll
      for (int nt = 0; nt < 4; ++nt) {
        const int dr = nt * 16 + l15;
        const bf16x8 vf = *(const bf16x8*)((char*)Vt2 + dr * 128 + (((ks * 4 + g) ^ (dr & 7)) << 4));
        o[nt] = __builtin_amdgcn_mfma_f32_16x16x32_bf16(pa, vf, o[nt], 0, 0, 0);
      }
    }
    #pragma unroll
    for (int r = 0; r < 4; ++r) {
      const float inv = 1.0f / l_acc[r];
      const int qrow = c * 64 + 16 * wl + g * 4 + r;
      #pragma unroll
      for (int nt = 0; nt < 4; ++nt)
        catb[((size_t)b * L_ + qrow) * DIM_ + h * 64 + nt * 16 + l15] = f2b(o[nt][r] * inv);
    }
  }
}

// ---------------------------------------------------------------------------
extern "C" void kernel_launch(void* const* d_in, const int* in_sizes, int n_in,
                              void* d_out, int out_size, void* d_ws, size_t ws_size,
                              hipStream_t stream) {
  (void)in_sizes; (void)n_in; (void)out_size; (void)ws_size;
  const float* x      = (const float*)d_in[0];
  const float* wq1    = (const float*)d_in[1];
  const float* bq1    = (const float*)d_in[2];
  const float* ln_g   = (const float*)d_in[3];
  const float* ln_b   = (const float*)d_in[4];
  const float* shifts = (const float*)d_in[5];
  const float* freqs  = (const float*)d_in[6];
  const float* wq     = (const float*)d_in[7];
  const float* wk     = (const float*)d_in[8];
  const float* wv     = (const float*)d_in[9];
  const float* wo     = (const float*)d_in[10];
  const float* bo     = (const float*)d_in[11];
  float* out = (float*)d_out;

  char* p = (char*)d_ws;
  bf16_t* amp_b  = (bf16_t*)p; p += (size_t)2 * B_ * L_ * HD_ * 2;
  float* phase   = (float*)p;  p += (size_t)2 * B_ * L_ * HD_ * 4;
  bf16_t* xb     = (bf16_t*)p; p += (size_t)B_ * L_ * DIM_ * 2;
  bf16_t* wt_qkv = (bf16_t*)p; p += (size_t)2688 * 1024 * 2;
  bf16_t* wt_o   = (bf16_t*)p; p += (size_t)1024 * 1024 * 2;
  bf16_t* qb     = (bf16_t*)p; p += (size_t)B_ * TH_ * L_ * HD_ * 2;
  bf16_t* kb     = (bf16_t*)p; p += (size_t)B_ * TH_ * L_ * HD_ * 2;
  bf16_t* vtb    = (bf16_t*)p; p += (size_t)B_ * TH_ * L_ * HD_ * 2;
  bf16_t* catb   = (bf16_t*)p;

  k_prep<<<dim3(9856), dim3(256), 0, stream>>>(x, wq1, bq1, ln_g, ln_b,
                                               wq, wk, wv, wo,
                                               xb, wt_qkv, wt_o, amp_b, phase);
  k_mm1q<<<dim3(336), dim3(512), 0, stream>>>(xb, wt_qkv, qb, kb, vtb);
  k_flash2<<<dim3(512), dim3(512), 0, stream>>>(qb, kb, vtb, catb,
                                                xb, amp_b, phase, shifts, freqs);
  k_mm0<<<dim3(256), dim3(256), 0, stream>>>(catb, wt_o, bo, out);
}